// Round 10
// baseline (1218.011 us; speedup 1.0000x reference)
//
#include <hip/hip_runtime.h>
#include <stdint.h>

typedef __fp16 half2v __attribute__((ext_vector_type(2)));
typedef __fp16 half8v __attribute__((ext_vector_type(8)));
typedef float floatx4 __attribute__((ext_vector_type(4)));

#define Lr   512
#define Br   128
#define DINr 256
#define DHr  512

__device__ __forceinline__ float fdot2(half2v a, half2v b, float c) {
    return __builtin_amdgcn_fdot2(a, b, c, false);
}
__device__ __forceinline__ uint32_t pk_u32(float lo, float hi) {
    half2v h = __builtin_amdgcn_cvt_pkrtz(lo, hi);
    return __builtin_bit_cast(uint32_t, h);
}
__device__ __forceinline__ half2v u32_h2(uint32_t u) {
    return __builtin_bit_cast(half2v, u);
}

// ---------------------------------------------------------------------------
// Kernel W: convert Wx (f32 [256][512]) into MFMA-B-fragment-ordered f16.
// ---------------------------------------------------------------------------
__global__ __launch_bounds__(512)
void wxcvt_kernel(const float* __restrict__ Wx, __fp16* __restrict__ bt)
{
    const int gid = blockIdx.x * 512 + threadIdx.x;   // 256 blocks -> 131072
    const int k = gid >> 9;
    const int n = gid & 511;
    const int s = k >> 5, g = (k >> 3) & 3, j = k & 7;
    const int nt = n >> 4, r = n & 15;
    const int idx = ((((nt * 8 + s) * 4 + g) * 16 + r) * 8) + j;
    bt[idx] = (__fp16)Wx[gid];
}

// ---------------------------------------------------------------------------
// Kernel A: xp = x @ Wx + bx via f16 MFMA 16x16x32 (verified round 9).
// ---------------------------------------------------------------------------
__global__ __launch_bounds__(512)
void xp_mfma_kernel(const float* __restrict__ x, const __fp16* __restrict__ bt,
                    const float* __restrict__ bx, float* __restrict__ out)
{
    const int tid  = threadIdx.x;
    const int w    = tid >> 6;
    const int lane = tid & 63;
    const int g    = lane >> 4;
    const int r    = lane & 15;
    const int m0   = blockIdx.x * 128 + w * 16;

    const float* xrow = x + (size_t)(m0 + r) * DINr;
    half8v af[8];
    #pragma unroll
    for (int s = 0; s < 8; ++s) {
        const float4 u = *(const float4*)(xrow + 32 * s + 8 * g);
        const float4 v = *(const float4*)(xrow + 32 * s + 8 * g + 4);
        half8v a;
        a[0] = (__fp16)u.x; a[1] = (__fp16)u.y; a[2] = (__fp16)u.z; a[3] = (__fp16)u.w;
        a[4] = (__fp16)v.x; a[5] = (__fp16)v.y; a[6] = (__fp16)v.z; a[7] = (__fp16)v.w;
        af[s] = a;
    }

    const half8v* bt8 = (const half8v*)bt;

    #pragma unroll 4
    for (int nt = 0; nt < 32; ++nt) {
        floatx4 acc = {0.f, 0.f, 0.f, 0.f};
        #pragma unroll
        for (int s = 0; s < 8; ++s) {
            const half8v bf = bt8[((nt * 8 + s) * 4 + g) * 16 + r];
            acc = __builtin_amdgcn_mfma_f32_16x16x32_f16(af[s], bf, acc, 0, 0, 0);
        }
        const float bxv = bx[nt * 16 + r];
        #pragma unroll
        for (int q = 0; q < 4; ++q) {
            out[(size_t)(m0 + 4 * g + q) * DHr + nt * 16 + r] = acc[q] + bxv;
        }
    }
}

// ---------------------------------------------------------------------------
// Kernel B: persistent recurrence, wave-level k-split + SGPR h-broadcast.
// 128 blocks x 512 thr. Wave wv = (kh, cg): kh = wv>>2 (k-half), cg = wv&3.
// Lane l owns cols c0 = cg*128+l, c1 = c0+64; 128 k-pairs each (k-half kh):
// 96 pairs/col in regs + 32 pairs/col in LDS (b128 reads, same as r9).
// h distributed 2 pairs/lane (1 ds_read_b64), broadcast via v_readlane ->
// SGPR feeding v_dot2 directly: h traffic leaves the LDS pipe.
// Partner k-half partials exchanged via 2KB LDS; finish split kh=0/kh=1.
// Two __syncthreads per step; single h buffer (reads drain before barrier1).
// ---------------------------------------------------------------------------
__global__ __launch_bounds__(512)
void rnn_kernel(const float* __restrict__ h0, const float* __restrict__ Wh,
                const float* __restrict__ bh, float* __restrict__ out)
{
    const int tid  = threadIdx.x;
    const int b    = blockIdx.x;
    const int lane = tid & 63;
    const int wv   = tid >> 6;
    const int kh   = wv >> 2;                 // k-half (0: k<256, 1: k>=256)
    const int cg   = wv & 3;                  // column group of 128
    const int c0   = cg * 128 + lane;
    const int c1   = c0 + 64;
    const int myc  = kh ? c1 : c0;            // column this wave finishes

    __shared__ __align__(8)  uint32_t hbuf[256];     // packed h pairs (pair m = h[2m],h[2m+1])
    __shared__ float part[512];                      // cross-k-half partials
    __shared__ __align__(16) uint4 wldsA2[8][512];   // pairs 96..127, col c0
    __shared__ __align__(16) uint4 wldsB2[8][512];   // pairs 96..127, col c1

    // ---- stage Wh: pairs q (k = 2*(kh*128+q)) for cols c0, c1 ----
    half2v wr0[96], wr1[96];
    #pragma unroll
    for (int q = 0; q < 96; ++q) {
        const int k = 2 * (kh * 128 + q);
        const float* Wk  = Wh + (size_t)k * DHr;
        const float* Wk1 = Wk + DHr;
        wr0[q] = __builtin_amdgcn_cvt_pkrtz(Wk[c0], Wk1[c0]);
        wr1[q] = __builtin_amdgcn_cvt_pkrtz(Wk[c1], Wk1[c1]);
    }
    #pragma unroll
    for (int c = 0; c < 8; ++c) {
        uint4 qa, qb;
        uint32_t* qaw = (uint32_t*)&qa;
        uint32_t* qbw = (uint32_t*)&qb;
        #pragma unroll
        for (int jj = 0; jj < 4; ++jj) {
            const int q = 96 + 4 * c + jj;
            const int k = 2 * (kh * 128 + q);
            const float* Wk  = Wh + (size_t)k * DHr;
            const float* Wk1 = Wk + DHr;
            qaw[jj] = pk_u32(Wk[c0], Wk1[c0]);
            qbw[jj] = pk_u32(Wk[c1], Wk1[c1]);
        }
        wldsA2[c][tid] = qa;
        wldsB2[c][tid] = qb;
    }

    const float bhv = bh[myc];
    float xpv = out[(size_t)b * DHr + myc];   // xp for t=0 (from kernel A)

    if (tid < 256) {
        const float* h0b = h0 + (size_t)b * DHr + 2 * tid;
        hbuf[tid] = pk_u32(h0b[0], h0b[1]);
    }
    __syncthreads();

    #pragma unroll 1
    for (int t = 0; t < Lr; ++t) {
        // my 2 h-pairs of this k-half: pair indices kh*128 + 2*lane, +1
        const uint2 hp = *(const uint2*)&hbuf[kh * 128 + 2 * lane];

        float a0e = 0.f, a0o = 0.f, a1e = 0.f, a1o = 0.f;
        #pragma unroll
        for (int m = 0; m < 48; ++m) {        // pairs 0..95 (register weights)
            const uint32_t se = __builtin_amdgcn_readlane(hp.x, m);  // pair 2m
            const uint32_t so = __builtin_amdgcn_readlane(hp.y, m);  // pair 2m+1
            a0e = fdot2(u32_h2(se), wr0[2*m],   a0e);
            a1e = fdot2(u32_h2(se), wr1[2*m],   a1e);
            a0o = fdot2(u32_h2(so), wr0[2*m+1], a0o);
            a1o = fdot2(u32_h2(so), wr1[2*m+1], a1o);
        }
        #pragma unroll
        for (int c = 0; c < 8; ++c) {         // pairs 96..127 (LDS weights)
            const uint4 wa = wldsA2[c][tid];
            const uint4 wb = wldsB2[c][tid];
            const int m0 = 48 + 2 * c;
            const uint32_t se0 = __builtin_amdgcn_readlane(hp.x, m0);
            const uint32_t so0 = __builtin_amdgcn_readlane(hp.y, m0);
            const uint32_t se1 = __builtin_amdgcn_readlane(hp.x, m0 + 1);
            const uint32_t so1 = __builtin_amdgcn_readlane(hp.y, m0 + 1);
            a0e = fdot2(u32_h2(se0), u32_h2(wa.x), a0e);
            a1e = fdot2(u32_h2(se0), u32_h2(wb.x), a1e);
            a0o = fdot2(u32_h2(so0), u32_h2(wa.y), a0o);
            a1o = fdot2(u32_h2(so0), u32_h2(wb.y), a1o);
            a0e = fdot2(u32_h2(se1), u32_h2(wa.z), a0e);
            a1e = fdot2(u32_h2(se1), u32_h2(wb.z), a1e);
            a0o = fdot2(u32_h2(so1), u32_h2(wa.w), a0o);
            a1o = fdot2(u32_h2(so1), u32_h2(wb.w), a1o);
        }
        const float s0 = a0e + a0o;           // partial for c0 (this k-half)
        const float s1 = a1e + a1o;           // partial for c1

        // hand the NON-finished column's partial to the partner k-half wave
        part[kh ? c0 : c1] = kh ? s0 : s1;
        __syncthreads();                      // barrier 1

        const float sown = kh ? s1 : s0;
        const float o    = sown + part[myc] + xpv + bhv;
        const float e    = __expf(2.f * o);
        const float h    = 1.f - 2.f * __builtin_amdgcn_rcpf(e + 1.f);

        out[(size_t)(t * Br + b) * DHr + myc] = h;
        if (t + 1 < Lr)
            xpv = out[(size_t)((t + 1) * Br + b) * DHr + myc];  // prefetch xp

        const float hn = __shfl_xor(h, 1, 64);
        if (!(lane & 1))                      // pair (myc, myc+1) -> pair idx myc>>1
            hbuf[cg * 64 + kh * 32 + (lane >> 1)] = pk_u32(h, hn);
        __syncthreads();                      // barrier 2
    }
}

extern "C" void kernel_launch(void* const* d_in, const int* in_sizes, int n_in,
                              void* d_out, int out_size, void* d_ws, size_t ws_size,
                              hipStream_t stream) {
    (void)in_sizes; (void)n_in; (void)ws_size; (void)out_size;
    const float* x  = (const float*)d_in[0];
    const float* h0 = (const float*)d_in[1];
    const float* Wx = (const float*)d_in[2];
    const float* bx = (const float*)d_in[3];
    const float* Wh = (const float*)d_in[4];
    const float* bh = (const float*)d_in[5];
    float* out  = (float*)d_out;
    __fp16* bt  = (__fp16*)d_ws;   // 131072 * 2B = 256 KB of workspace

    wxcvt_kernel<<<dim3(256), dim3(512), 0, stream>>>(Wx, bt);
    xp_mfma_kernel<<<dim3(512), dim3(512), 0, stream>>>(x, bt, bx, out);
    rnn_kernel<<<dim3(128), dim3(512), 0, stream>>>(h0, Wh, bh, out);
}